// Round 7
// baseline (1002.175 us; speedup 1.0000x reference)
//
#include <hip/hip_runtime.h>
#include <hip/hip_bf16.h>

// Problem constants (fixed by the reference)
#define B_  64
#define T_  128
#define E_  300
#define EP  320     // E padded to multiple of 32 for MFMA K-loop
#define H_  512
#define G4  2048    // 4*H
#define R_  128     // 2*B (s1+s2 batched; shared LSTM weights)
#define C_  256
#define M_  512
#define TS  (T_ + 1)  // h time slots: slot 0 = h0, slot t+1 = h(t)
#define NB  128     // persistent-kernel grid: 2 streams x 4 rowblocks x 16 jblocks
#define SENT 0xFFFFFFFFFFFFFFFFULL   // 4x bf16 NaN — unreachable by real h

typedef short bf16x8 __attribute__((ext_vector_type(8)));
typedef float f32x4  __attribute__((ext_vector_type(4)));
#define MFMA(a, b, c) __builtin_amdgcn_mfma_f32_16x16x32_bf16((a), (b), (c), 0, 0, 0)

__device__ __forceinline__ float fsig(float x) { return 1.0f / (1.0f + __expf(-x)); }
__device__ __forceinline__ float ftanh(float x) {
    float a = fminf(fabsf(x), 15.0f);
    float e = __expf(2.0f * a);
    return copysignf((e - 1.0f) / (e + 1.0f), x);
}
__device__ __forceinline__ ushort f2bf(float f) {
    __hip_bfloat16 h = __float2bfloat16(f);
    return *reinterpret_cast<ushort*>(&h);
}
__device__ __forceinline__ float bf2f(ushort u) {
    __hip_bfloat16 h = *reinterpret_cast<__hip_bfloat16*>(&u);
    return __bfloat162float(h);
}

// ---------------------------------------------------------------------------
// P0 v2: VECTORIZED f32 -> bf16 conversion (round-6 verbatim).
// ---------------------------------------------------------------------------
__global__ __launch_bounds__(256) void k_cvt_all(
    const float* __restrict__ emb,
    const float* __restrict__ Wih_f, const float* __restrict__ Wih_b,
    const float* __restrict__ Whh_f, const float* __restrict__ Whh_b,
    const float* __restrict__ S1W,
    const float* __restrict__ s1_h0, const float* __restrict__ s2_h0,
    ushort* __restrict__ embB,
    ushort* __restrict__ WihBf, ushort* __restrict__ WihBb,
    ushort* __restrict__ WhhBf, ushort* __restrict__ WhhBb,
    ushort* __restrict__ S1WB,
    ushort* __restrict__ hfB, ushort* __restrict__ hbB)
{
    const int b = blockIdx.x;
    if (b >= 5056) {   // h0 init role: 128 blocks, one r each
        const int r = b - 5056;                      // 0..127
        const int rl = (r < B_) ? r : r - B_;
        const float* h0 = (r < B_) ? s1_h0 : s2_h0;  // [2][B][H]
        for (int u = threadIdx.x; u < 128; u += 256) {
            const int which = u >> 6;                // 0: fwd/hf, 1: bwd/hb
            const int c8 = (u & 63) * 8;
            const float* s = h0 + (long)which * B_ * H_ + (long)rl * H_ + c8;
            ushort* d = (which ? hbB : hfB) + (long)r * TS * H_ + c8;
            float4 f0 = *(const float4*)&s[0];
            float4 f1 = *(const float4*)&s[4];
            bf16x8 v;
            v[0] = (short)f2bf(f0.x); v[1] = (short)f2bf(f0.y);
            v[2] = (short)f2bf(f0.z); v[3] = (short)f2bf(f0.w);
            v[4] = (short)f2bf(f1.x); v[5] = (short)f2bf(f1.y);
            v[6] = (short)f2bf(f1.z); v[7] = (short)f2bf(f1.w);
            *(bf16x8*)d = v;
        }
        return;
    }
    const float* src; ushort* dst; int r0, sk, dk;
    if (b < 4000)      { src = emb;   dst = embB;  r0 = b * 8;          sk = E_;    dk = EP; }
    else if (b < 4256) { src = Wih_f; dst = WihBf; r0 = (b - 4000) * 8; sk = E_;    dk = EP; }
    else if (b < 4512) { src = Wih_b; dst = WihBb; r0 = (b - 4256) * 8; sk = E_;    dk = EP; }
    else if (b < 4768) { src = Whh_f; dst = WhhBf; r0 = (b - 4512) * 8; sk = H_;    dk = H_; }
    else if (b < 5024) { src = Whh_b; dst = WhhBb; r0 = (b - 4768) * 8; sk = H_;    dk = H_; }
    else               { src = S1W;   dst = S1WB;  r0 = (b - 5024) * 8; sk = 2*H_;  dk = 2*H_; }
    const int upr = dk >> 3;            // 8-elem units per row
    for (int u = threadIdx.x; u < 8 * upr; u += 256) {
        const int r  = r0 + u / upr;
        const int c8 = (u % upr) * 8;
        const float* s = &src[(long)r * sk + c8];
        bf16x8 v;
        if (c8 + 8 <= sk) {
            float4 f0 = *(const float4*)&s[0];
            float4 f1 = *(const float4*)&s[4];
            v[0] = (short)f2bf(f0.x); v[1] = (short)f2bf(f0.y);
            v[2] = (short)f2bf(f0.z); v[3] = (short)f2bf(f0.w);
            v[4] = (short)f2bf(f1.x); v[5] = (short)f2bf(f1.y);
            v[6] = (short)f2bf(f1.z); v[7] = (short)f2bf(f1.w);
        } else {
#pragma unroll
            for (int e = 0; e < 8; ++e)
                v[e] = (c8 + e < sk) ? (short)f2bf(s[e]) : (short)0;
        }
        *(bf16x8*)&dst[(long)r * dk + c8] = v;
    }
}

// ---------------------------------------------------------------------------
// K2 v13: v8 sync protocol VERBATIM (poll / stores / barriers untouched —
// the proven 3.55us/step handoff), with K1's xW GEMM FOLDED INTO THE WAIT
// SLACK. Per step t the block computes xW(t+1) = emb(toks(t+1)) @ Wih^T + b
// for its own 128 (gate,j) columns:
//   - Wih tile (128 x 320, 80KB) staged to LDS once at prologue.
//   - Aemb(t+1) (32 x 320, 20KB) staged per step from embB.
//   - Both use As-style chunk-rotation swizzle (conflict-free, no padding).
//   - xW published to xWs LDS as bf16 with bias added BEFORE conversion and
//     the same K-order as the old K1 -> bit-identical xW values.
//   - Reads/writes of xWs are separated by the EXISTING two barriers
//     (read after sync#1 into regs; publish after sync#2). No new syncs.
// K1 kernel + xf/xb buffers deleted (-134MB xW write, -134MB xW read).
// ---------------------------------------------------------------------------
__global__ __launch_bounds__(256, 1) void k_recur(
    const int* __restrict__ s1, const int* __restrict__ s2,
    const int* __restrict__ l1, const int* __restrict__ l2,
    const ushort* __restrict__ embB,
    const ushort* __restrict__ WihBf, const ushort* __restrict__ WihBb,
    const float* __restrict__ b_f, const float* __restrict__ b_b,
    ushort* __restrict__ hfB, ushort* __restrict__ hbB,
    const ushort* __restrict__ WhhBf, const ushort* __restrict__ WhhBb,
    const float* __restrict__ s1_c0, const float* __restrict__ s2_c0)
{
    const int bx = blockIdx.x;
    const int s  = bx >> 6;          // stream: 0 fwd, 1 bwd
    const int rb = (bx >> 4) & 3;    // row block of 32
    const int jb = bx & 15;          // j block of 32
    const int r0 = rb * 32, j0 = jb * 32;

    const ushort* Whh  = s ? WhhBb : WhhBf;
    const ushort* WihB = s ? WihBb : WihBf;
    const float*  bias = s ? b_b : b_f;
    ushort* hB = s ? hbB : hfB;

    const int tid = threadIdx.x;
    const int lane = tid & 63;
    const int g = tid >> 6;          // wave = gate (i,f,g,o)
    const int l15 = lane & 15, q8 = (lane >> 4) * 8;

    __shared__ __align__(16) ushort As[32][520];   // h staging (v8 verbatim)
    __shared__ float Gs[4][32][33];                // gate pre-acts 32 x 32
    __shared__ __align__(16) ushort WihL[128 * 320];  // Wih tile, swizzled
    __shared__ __align__(16) ushort Aemb[32 * 320];   // emb rows, swizzled
    __shared__ __align__(16) ushort xWs[4][32][36];   // xW(t) bf16 (bias incl)
    __shared__ int toks[32];
    __shared__ int Ls[32];

    // Whh fragments resident in registers (v8 verbatim)
    bf16x8 bfr[2][16];
#pragma unroll
    for (int nt = 0; nt < 2; ++nt) {
        const ushort* brow = &Whh[((long)g * H_ + j0 + nt * 16 + l15) * H_];
#pragma unroll
        for (int ks = 0; ks < 16; ++ks)
            bfr[nt][ks] = *(const bf16x8*)&brow[ks * 32 + q8];
    }

    // cell ownership (v8 verbatim)
    const int rr = tid >> 3, jj = (tid & 7) * 4;
    const int rg_ = r0 + rr;
    const int rl  = (rg_ < B_) ? rg_ : rg_ - B_;
    const float* c0p = (rg_ < B_) ? s1_c0 : s2_c0;   // [2][B][H]
    float cst[4];
#pragma unroll
    for (int cc = 0; cc < 4; ++cc)
        cst[cc] = c0p[(long)s * B_ * H_ + (long)rl * H_ + j0 + jj + cc];

    // A staging ids (v8 verbatim)
    const int arow = tid >> 3, aseg = tid & 7;
    const int swz = ((aseg + arow) & 7) * 8;

    // per-lane bias for xW publish (wave g, its two 16-col tiles)
    const float biasv0 = bias[g * H_ + j0 + l15];
    const float biasv1 = bias[g * H_ + j0 + 16 + l15];
    const int cr0 = g * 32 + l15, cr1 = g * 32 + 16 + l15;

    // ---- prologue: lengths + toks(0) ----
    if (tid < 32) {
        int rg = r0 + tid;
        int L = (rg < B_) ? l1[rg] : l2[rg - B_];
        Ls[tid] = L;
        int tt = s ? ((L > 0) ? L - 1 : 0) : 0;
        toks[tid] = (rg < B_) ? s1[rg * T_ + tt] : s2[(rg - B_) * T_ + tt];
    }
    // stage Wih tile -> LDS (swizzled chunks; 128 rows x 320)
    for (int u = tid; u < 5120; u += 256) {
        int cr = u / 40, un = u % 40;
        int grow = (cr >> 5) * H_ + j0 + (cr & 31);
        int pos = (un >> 3) * 64 + ((((un & 7) + cr) & 7) << 3);
        *(bf16x8*)&WihL[cr * 320 + pos] =
            *(const bf16x8*)&WihB[(long)grow * EP + un * 8];
    }
    __syncthreads();
    // stage Aemb(0)
    for (int u = tid; u < 1280; u += 256) {
        int row = u / 40, un = u % 40;
        int pos = (un >> 3) * 64 + ((((un & 7) + row) & 7) << 3);
        *(bf16x8*)&Aemb[row * 320 + pos] =
            *(const bf16x8*)&embB[(long)toks[row] * EP + un * 8];
    }
    __syncthreads();
    // xW(0) GEMM + publish
    {
        f32x4 ax[2][2] = {};
#pragma unroll
        for (int kk = 0; kk < 10; ++kk) {
            int e = kk * 32 + q8;
            int sb = (e >> 6) * 64;
            int ch = (e >> 3) & 7;
            bf16x8 a0 = *(const bf16x8*)&Aemb[l15 * 320 + sb + (((ch + l15) & 7) << 3)];
            bf16x8 a1 = *(const bf16x8*)&Aemb[(16 + l15) * 320 + sb + (((ch + 16 + l15) & 7) << 3)];
            bf16x8 b0 = *(const bf16x8*)&WihL[cr0 * 320 + sb + (((ch + cr0) & 7) << 3)];
            bf16x8 b1 = *(const bf16x8*)&WihL[cr1 * 320 + sb + (((ch + cr1) & 7) << 3)];
            ax[0][0] = MFMA(a0, b0, ax[0][0]);
            ax[0][1] = MFMA(a0, b1, ax[0][1]);
            ax[1][0] = MFMA(a1, b0, ax[1][0]);
            ax[1][1] = MFMA(a1, b1, ax[1][1]);
        }
#pragma unroll
        for (int mt = 0; mt < 2; ++mt)
#pragma unroll
            for (int rgx = 0; rgx < 4; ++rgx) {
                int row = mt * 16 + (lane >> 4) * 4 + rgx;
                xWs[g][row][l15]      = f2bf(ax[mt][0][rgx] + biasv0);
                xWs[g][row][16 + l15] = f2bf(ax[mt][1][rgx] + biasv1);
            }
    }
    __syncthreads();

    for (int t = 0; t < T_; ++t) {
        // tokens for t+1 (consumed after sync#1)
        if (t + 1 < T_ && tid < 32) {
            int L = Ls[tid], tq = t + 1;
            int tt = s ? ((tq < L) ? L - 1 - tq : tq) : tq;
            int rg = r0 + tid;
            toks[tid] = (rg < B_) ? s1[rg * T_ + tt] : s2[(rg - B_) * T_ + tt];
        }

        // h(t): poll the data itself (v8 VERBATIM)
        const ushort* hrow = &hB[((long)(r0 + arow) * TS + t) * H_ + aseg * 8];
        unsigned long long hv[16];
        bool ok;
        do {
#pragma unroll
            for (int i = 0; i < 16; ++i) {
                const unsigned long long* p8 =
                    (const unsigned long long*)(hrow + (i >> 1) * 64 + (i & 1) * 4);
                hv[i] = __hip_atomic_load(p8, __ATOMIC_RELAXED,
                                          __HIP_MEMORY_SCOPE_AGENT);
            }
            ok = true;
#pragma unroll
            for (int i = 0; i < 16; ++i)
                ok = ok && (hv[i] != SENT);
        } while (!ok);

#pragma unroll
        for (int sl = 0; sl < 8; ++sl) {
            uint4 av;
            av.x = (uint)hv[2 * sl];       av.y = (uint)(hv[2 * sl] >> 32);
            av.z = (uint)hv[2 * sl + 1];   av.w = (uint)(hv[2 * sl + 1] >> 32);
            *(uint4*)&As[arow][sl * 64 + swz] = av;
        }
        __syncthreads();   // sync#1

        // xW(t) -> registers (published last step; xWs stable until sync#2)
        uint2 xwr[4];
#pragma unroll
        for (int gg = 0; gg < 4; ++gg)
            xwr[gg] = *(const uint2*)&xWs[gg][rr][jj];

        // Whh MFMA (v8 verbatim)
        f32x4 acc[2][2] = {};
#pragma unroll
        for (int ks = 0; ks < 16; ++ks) {
            const int e  = ks * 32 + q8;
            const int sl = e >> 6;
            const int c  = (e >> 3) & 7;
            bf16x8 a0 = *(const bf16x8*)&As[l15][sl * 64 + (((c + l15) & 7) << 3)];
            bf16x8 a1 = *(const bf16x8*)&As[16 + l15][sl * 64 + (((c + l15) & 7) << 3)];
            acc[0][0] = MFMA(a0, bfr[0][ks], acc[0][0]);
            acc[0][1] = MFMA(a0, bfr[1][ks], acc[0][1]);
            acc[1][0] = MFMA(a1, bfr[0][ks], acc[1][0]);
            acc[1][1] = MFMA(a1, bfr[1][ks], acc[1][1]);
        }

        // stage Aemb(t+1) (global -> LDS; latency overlaps MFMA above)
        if (t + 1 < T_) {
            for (int u = tid; u < 1280; u += 256) {
                int row = u / 40, un = u % 40;
                int pos = (un >> 3) * 64 + ((((un & 7) + row) & 7) << 3);
                *(bf16x8*)&Aemb[row * 320 + pos] =
                    *(const bf16x8*)&embB[(long)toks[row] * EP + un * 8];
            }
        }

        // publish gate pre-acts (v8 verbatim)
#pragma unroll
        for (int mt = 0; mt < 2; ++mt)
#pragma unroll
            for (int nt = 0; nt < 2; ++nt)
#pragma unroll
                for (int rg2 = 0; rg2 < 4; ++rg2)
                    Gs[g][mt * 16 + (lane >> 4) * 4 + rg2][nt * 16 + l15] =
                        acc[mt][nt][rg2];
        __syncthreads();   // sync#2

        // xW(t+1) GEMM + publish (xWs safe to overwrite: reads were pre-sync#2)
        if (t + 1 < T_) {
            f32x4 ax[2][2] = {};
#pragma unroll
            for (int kk = 0; kk < 10; ++kk) {
                int e = kk * 32 + q8;
                int sb = (e >> 6) * 64;
                int ch = (e >> 3) & 7;
                bf16x8 a0 = *(const bf16x8*)&Aemb[l15 * 320 + sb + (((ch + l15) & 7) << 3)];
                bf16x8 a1 = *(const bf16x8*)&Aemb[(16 + l15) * 320 + sb + (((ch + 16 + l15) & 7) << 3)];
                bf16x8 b0 = *(const bf16x8*)&WihL[cr0 * 320 + sb + (((ch + cr0) & 7) << 3)];
                bf16x8 b1 = *(const bf16x8*)&WihL[cr1 * 320 + sb + (((ch + cr1) & 7) << 3)];
                ax[0][0] = MFMA(a0, b0, ax[0][0]);
                ax[0][1] = MFMA(a0, b1, ax[0][1]);
                ax[1][0] = MFMA(a1, b0, ax[1][0]);
                ax[1][1] = MFMA(a1, b1, ax[1][1]);
            }
#pragma unroll
            for (int mt = 0; mt < 2; ++mt)
#pragma unroll
                for (int rgx = 0; rgx < 4; ++rgx) {
                    int row = mt * 16 + (lane >> 4) * 4 + rgx;
                    xWs[g][row][l15]      = f2bf(ax[mt][0][rgx] + biasv0);
                    xWs[g][row][16 + l15] = f2bf(ax[mt][1][rgx] + biasv1);
                }
        }

        // fused cell update for 4 cols (v8 verbatim, xw from xwr regs)
        ushort hp[4];
#pragma unroll
        for (int cc = 0; cc < 4; ++cc) {
            uint xv0 = (cc < 2) ? xwr[0].x : xwr[0].y;
            uint xv1 = (cc < 2) ? xwr[1].x : xwr[1].y;
            uint xv2 = (cc < 2) ? xwr[2].x : xwr[2].y;
            uint xv3 = (cc < 2) ? xwr[3].x : xwr[3].y;
            int sh = (cc & 1) * 16;
            float gi = Gs[0][rr][jj + cc] + bf2f((ushort)(xv0 >> sh));
            float gf = Gs[1][rr][jj + cc] + bf2f((ushort)(xv1 >> sh));
            float gg = Gs[2][rr][jj + cc] + bf2f((ushort)(xv2 >> sh));
            float go = Gs[3][rr][jj + cc] + bf2f((ushort)(xv3 >> sh));
            cst[cc] = fsig(gf) * cst[cc] + fsig(gi) * ftanh(gg);
            hp[cc] = f2bf(fsig(go) * ftanh(cst[cc]));
        }
        unsigned long long pk = (unsigned long long)hp[0]
                              | ((unsigned long long)hp[1] << 16)
                              | ((unsigned long long)hp[2] << 32)
                              | ((unsigned long long)hp[3] << 48);
        __hip_atomic_store(
            (unsigned long long*)&hB[((long)rg_ * TS + t + 1) * H_ + j0 + jj],
            pk, __ATOMIC_RELAXED, __HIP_MEMORY_SCOPE_AGENT);
    }
}

// ---------------------------------------------------------------------------
// K3 FUSED (round-5/6 verbatim, passed): U acc-resident, scores via shfl
// reduce + LDS atomicAdd, masked softmax, pool.
// ---------------------------------------------------------------------------
__global__ __launch_bounds__(256) void k_attn_fused(
    const ushort* __restrict__ hfB, const ushort* __restrict__ hbB,
    const int* __restrict__ l1, const int* __restrict__ l2,
    const ushort* __restrict__ S1WB, const float* __restrict__ S2W,
    float* __restrict__ pooled)
{
    const int r = blockIdx.x;
    const int L = (r < B_) ? l1[r] : l2[r - B_];
    const int tid = threadIdx.x;
    const int lane = tid & 63, w = tid >> 6;
    const int wm = w & 1, wn = w >> 1;
    const int l15 = lane & 15, q8 = (lane >> 4) * 8;

    __shared__ __align__(16) ushort As[128][72];   // 128 t-rows x 64 k
    __shared__ __align__(16) ushort Bs[256][72];   // 256 c-rows x 64 k
    __shared__ float sc[T_];
    __shared__ float att[T_];

    if (tid < T_) sc[tid] = 0.0f;

    f32x4 acc[4][8] = {};

    for (int k0 = 0; k0 < 2 * H_; k0 += 64) {
#pragma unroll
        for (int p = 0; p < 4; ++p) {   // A: 128 rows x 64 k
            int u = tid + p * 256;
            int row = u >> 3, seg = u & 7;
            int k = k0 + seg * 8;
            long idx;
            const ushort* src;
            if (k0 < H_) {
                src = hfB; idx = ((long)r * TS + row + 1) * H_ + k;
            } else {
                int tt = (row < L) ? (L - 1 - row) : row;
                src = hbB; idx = ((long)r * TS + tt + 1) * H_ + (k - H_);
            }
            *(uint4*)&As[row][seg * 8] = *(const uint4*)&src[idx];
        }
#pragma unroll
        for (int p = 0; p < 8; ++p) {   // B: 256 c-rows x 64 k
            int u = tid + p * 256;
            int row = u >> 3, seg = u & 7;
            *(uint4*)&Bs[row][seg * 8] =
                *(const uint4*)&S1WB[(long)row * (2 * H_) + k0 + seg * 8];
        }
        __syncthreads();
#pragma unroll
        for (int ks = 0; ks < 2; ++ks) {
            bf16x8 af[4], bfr[8];
#pragma unroll
            for (int mt = 0; mt < 4; ++mt)
                af[mt] = *(const bf16x8*)&As[wm * 64 + mt * 16 + l15][ks * 32 + q8];
#pragma unroll
            for (int nt = 0; nt < 8; ++nt)
                bfr[nt] = *(const bf16x8*)&Bs[wn * 128 + nt * 16 + l15][ks * 32 + q8];
#pragma unroll
            for (int mt = 0; mt < 4; ++mt)
#pragma unroll
                for (int nt = 0; nt < 8; ++nt)
                    acc[mt][nt] = MFMA(af[mt], bfr[nt], acc[mt][nt]);
        }
        __syncthreads();
    }

    float s2r[8];
#pragma unroll
    for (int nt = 0; nt < 8; ++nt)
        s2r[nt] = S2W[wn * 128 + nt * 16 + l15];
#pragma unroll
    for (int mt = 0; mt < 4; ++mt)
#pragma unroll
        for (int rg = 0; rg < 4; ++rg) {
            float v = 0.0f;
#pragma unroll
            for (int nt = 0; nt < 8; ++nt)
                v += ftanh(acc[mt][nt][rg]) * s2r[nt];
            v += __shfl_xor(v, 1);
            v += __shfl_xor(v, 2);
            v += __shfl_xor(v, 4);
            v += __shfl_xor(v, 8);
            if (l15 == 0)
                atomicAdd(&sc[wm * 64 + mt * 16 + (lane >> 4) * 4 + rg], v);
        }
    __syncthreads();

    float mx = -1e30f;
    for (int tt = 0; tt < L; ++tt) mx = fmaxf(mx, sc[tt]);
    __syncthreads();
    if (tid < T_) att[tid] = (tid < L) ? __expf(sc[tid] - mx) : 0.0f;
    __syncthreads();
    float sum = 0.0f;
    for (int tt = 0; tt < L; ++tt) sum += att[tt];
    float inv = 1.0f / sum;

    for (int p = tid; p < 512; p += 256) {
        float a0 = 0.0f, a1 = 0.0f;
        if (p < 256) {
            int d = p * 2;
            for (int tt = 0; tt < L; ++tt) {
                uint hv = *(const uint*)&hfB[((long)r * TS + tt + 1) * H_ + d];
                a0 += att[tt] * bf2f((ushort)(hv & 0xffff));
                a1 += att[tt] * bf2f((ushort)(hv >> 16));
            }
            pooled[(long)r * (2 * H_) + d]     = a0 * inv;
            pooled[(long)r * (2 * H_) + d + 1] = a1 * inv;
        } else {
            int d = (p - 256) * 2;
            for (int tt = 0; tt < L; ++tt) {
                uint hv = *(const uint*)&hbB[((long)r * TS + (L - tt)) * H_ + d];
                a0 += att[tt] * bf2f((ushort)(hv & 0xffff));
                a1 += att[tt] * bf2f((ushort)(hv >> 16));
            }
            pooled[(long)r * (2 * H_) + H_ + d]     = a0 * inv;
            pooled[(long)r * (2 * H_) + H_ + d + 1] = a1 * inv;
        }
    }
}

// ---------------------------------------------------------------------------
// K4a: om[b][mm] = merged[b] . mlpW[mm] + mlpb[mm] (unchanged).
// ---------------------------------------------------------------------------
__global__ __launch_bounds__(256) void k_mlp1(
    const float* __restrict__ pooled,
    const float* __restrict__ mlpW, const float* __restrict__ mlpb,
    float* __restrict__ om)
{
    const int mg = blockIdx.x;      // 0..7
    const int b  = blockIdx.y;      // 0..63
    const int tid = threadIdx.x;
    const int lane = tid & 63, w = tid >> 6;

    __shared__ __align__(16) float sm[2048];

#pragma unroll
    for (int it = 0; it < 8; ++it) {
        int d = tid + it * 256;
        float v;
        if (d < 1024) {
            v = pooled[(long)b * 1024 + d] + pooled[(long)(B_ + b) * 1024 + d];
        } else {
            int dd = d - 1024;
            float x = pooled[(long)b * 1024 + dd] - pooled[(long)(B_ + b) * 1024 + dd];
            v = x * x;
        }
        sm[d] = v;
    }
    __syncthreads();

    for (int i = 0; i < 16; ++i) {
        int mm = mg * 64 + w * 16 + i;
        const float* wrow = &mlpW[(long)mm * 2048];
        float ax = 0.f, ay = 0.f, az = 0.f, aw = 0.f;
#pragma unroll
        for (int it = 0; it < 8; ++it) {
            int k = it * 256 + lane * 4;
            float4 wv = *(const float4*)&wrow[k];
            float4 sv = *(const float4*)&sm[k];
            ax += wv.x * sv.x; ay += wv.y * sv.y;
            az += wv.z * sv.z; aw += wv.w * sv.w;
        }
        float ssum = (ax + ay) + (az + aw);
        for (int off = 32; off; off >>= 1) ssum += __shfl_down(ssum, off);
        if (lane == 0) om[(long)b * M_ + mm] = ssum + mlpb[mm];
    }
}

// K4b: out[b] = sigmoid(om[b] . outW + outb)   (CLS = 1)
__global__ __launch_bounds__(256) void k_final(
    const float* __restrict__ om,
    const float* __restrict__ outW, const float* __restrict__ outb,
    float* __restrict__ out)
{
    const int b = blockIdx.x;
    const int tid = threadIdx.x;
    __shared__ float red[256];
    float p = om[(long)b * M_ + tid] * outW[tid]
            + om[(long)b * M_ + 256 + tid] * outW[256 + tid];
    red[tid] = p;
    __syncthreads();
    for (int off = 128; off > 0; off >>= 1) {
        if (tid < off) red[tid] += red[tid + off];
        __syncthreads();
    }
    if (tid == 0) out[b] = 1.0f / (1.0f + __expf(-(red[0] + outb[0])));
}

// ---------------------------------------------------------------------------
extern "C" void kernel_launch(void* const* d_in, const int* in_sizes, int n_in,
                              void* d_out, int out_size, void* d_ws, size_t ws_size,
                              hipStream_t stream)
{
    const int*   s1    = (const int*)d_in[0];
    const int*   s2    = (const int*)d_in[1];
    const int*   l1    = (const int*)d_in[2];
    const int*   l2    = (const int*)d_in[3];
    const float* s1_h0 = (const float*)d_in[4];
    const float* s1_c0 = (const float*)d_in[5];
    const float* s2_h0 = (const float*)d_in[6];
    const float* s2_c0 = (const float*)d_in[7];
    const float* emb   = (const float*)d_in[8];
    const float* Wih_f = (const float*)d_in[9];
    const float* Whh_f = (const float*)d_in[10];
    const float* b_f   = (const float*)d_in[11];
    const float* Wih_b = (const float*)d_in[12];
    const float* Whh_b = (const float*)d_in[13];
    const float* b_b   = (const float*)d_in[14];
    const float* S1W   = (const float*)d_in[15];
    const float* S2W   = (const float*)d_in[16];
    const float* mlpW  = (const float*)d_in[17];
    const float* mlpb  = (const float*)d_in[18];
    const float* outW  = (const float*)d_in[19];
    const float* outb  = (const float*)d_in[20];
    float* out = (float*)d_out;

    // Workspace carve (all 16B-aligned); xf/xb eliminated by the K1 fusion.
    ushort* p16 = (ushort*)d_ws;
    ushort* embB  = p16;  p16 += (long)32000 * EP;
    ushort* WihBf = p16;  p16 += (long)G4 * EP;
    ushort* WihBb = p16;  p16 += (long)G4 * EP;
    ushort* WhhBf = p16;  p16 += (long)G4 * H_;
    ushort* WhhBb = p16;  p16 += (long)G4 * H_;
    ushort* S1WB  = p16;  p16 += (long)C_ * 2 * H_;
    ushort* hfB   = p16;  p16 += (long)R_ * TS * H_;
    ushort* hbB   = p16;  p16 += (long)R_ * TS * H_;
    float* pf = (float*)p16;
    float* pooled = pf;   pf += (long)R_ * 2 * H_;
    float* om     = pf;   pf += (long)B_ * M_;

    // sentinel-fill h arrays (0xFF bytes -> every 8B chunk = SENT); the
    // cvt_all init-role then writes real h0 into slot 0. hfB/hbB contiguous.
    hipMemsetAsync(hfB, 0xFF, (size_t)2 * R_ * TS * H_ * sizeof(ushort), stream);

    // P0 v2: vectorized weight conversion + h0 init
    k_cvt_all<<<5184, 256, 0, stream>>>(emb, Wih_f, Wih_b, Whh_f, Whh_b, S1W,
                                        s1_h0, s2_h0,
                                        embB, WihBf, WihBb, WhhBf, WhhBb, S1WB,
                                        hfB, hbB);

    // K2 v13: recurrence with xW GEMM folded into the wait slack (K1 deleted)
    k_recur<<<NB, 256, 0, stream>>>(s1, s2, l1, l2, embB, WihBf, WihBb,
                                    b_f, b_b, hfB, hbB, WhhBf, WhhBb,
                                    s1_c0, s2_c0);

    // K3: fused attention (GEMM + scores + softmax + pool)
    k_attn_fused<<<R_, 256, 0, stream>>>(hfB, hbB, l1, l2, S1WB, S2W, pooled);

    // K4: MLP head
    k_mlp1<<<dim3(8, B_), 256, 0, stream>>>(pooled, mlpW, mlpb, om);
    k_final<<<B_, 256, 0, stream>>>(om, outW, outb, out);
}

// Round 8
// 950.500 us; speedup vs baseline: 1.0544x; 1.0544x over previous
//
#include <hip/hip_runtime.h>
#include <hip/hip_bf16.h>

// Problem constants (fixed by the reference)
#define B_  64
#define T_  128
#define E_  300
#define EP  320     // E padded to multiple of 32 for MFMA K-loop
#define H_  512
#define G4  2048    // 4*H
#define R_  128     // 2*B (s1+s2 batched; shared LSTM weights)
#define C_  256
#define M_  512
#define TS  (T_ + 1)  // h time slots: slot 0 = h0, slot t+1 = h(t)
#define NB  128     // persistent-kernel grid: 2 streams x 4 rowblocks x 16 jblocks
#define SENT 0xFFFFFFFFFFFFFFFFULL   // 4x bf16 NaN — unreachable by real h

typedef short bf16x8 __attribute__((ext_vector_type(8)));
typedef float f32x4  __attribute__((ext_vector_type(4)));
#define MFMA(a, b, c) __builtin_amdgcn_mfma_f32_16x16x32_bf16((a), (b), (c), 0, 0, 0)

__device__ __forceinline__ float fsig(float x) { return 1.0f / (1.0f + __expf(-x)); }
__device__ __forceinline__ float ftanh(float x) {
    float a = fminf(fabsf(x), 15.0f);
    float e = __expf(2.0f * a);
    return copysignf((e - 1.0f) / (e + 1.0f), x);
}
__device__ __forceinline__ ushort f2bf(float f) {
    __hip_bfloat16 h = __float2bfloat16(f);
    return *reinterpret_cast<ushort*>(&h);
}
__device__ __forceinline__ float bf2f(ushort u) {
    __hip_bfloat16 h = *reinterpret_cast<__hip_bfloat16*>(&u);
    return __bfloat162float(h);
}

// ---------------------------------------------------------------------------
// P0 v2: VECTORIZED f32 -> bf16 conversion (round-6 verbatim).
// ---------------------------------------------------------------------------
__global__ __launch_bounds__(256) void k_cvt_all(
    const float* __restrict__ emb,
    const float* __restrict__ Wih_f, const float* __restrict__ Wih_b,
    const float* __restrict__ Whh_f, const float* __restrict__ Whh_b,
    const float* __restrict__ S1W,
    const float* __restrict__ s1_h0, const float* __restrict__ s2_h0,
    ushort* __restrict__ embB,
    ushort* __restrict__ WihBf, ushort* __restrict__ WihBb,
    ushort* __restrict__ WhhBf, ushort* __restrict__ WhhBb,
    ushort* __restrict__ S1WB,
    ushort* __restrict__ hfB, ushort* __restrict__ hbB)
{
    const int b = blockIdx.x;
    if (b >= 5056) {   // h0 init role: 128 blocks, one r each
        const int r = b - 5056;                      // 0..127
        const int rl = (r < B_) ? r : r - B_;
        const float* h0 = (r < B_) ? s1_h0 : s2_h0;  // [2][B][H]
        for (int u = threadIdx.x; u < 128; u += 256) {
            const int which = u >> 6;                // 0: fwd/hf, 1: bwd/hb
            const int c8 = (u & 63) * 8;
            const float* s = h0 + (long)which * B_ * H_ + (long)rl * H_ + c8;
            ushort* d = (which ? hbB : hfB) + (long)r * TS * H_ + c8;
            float4 f0 = *(const float4*)&s[0];
            float4 f1 = *(const float4*)&s[4];
            bf16x8 v;
            v[0] = (short)f2bf(f0.x); v[1] = (short)f2bf(f0.y);
            v[2] = (short)f2bf(f0.z); v[3] = (short)f2bf(f0.w);
            v[4] = (short)f2bf(f1.x); v[5] = (short)f2bf(f1.y);
            v[6] = (short)f2bf(f1.z); v[7] = (short)f2bf(f1.w);
            *(bf16x8*)d = v;
        }
        return;
    }
    const float* src; ushort* dst; int r0, sk, dk;
    if (b < 4000)      { src = emb;   dst = embB;  r0 = b * 8;          sk = E_;    dk = EP; }
    else if (b < 4256) { src = Wih_f; dst = WihBf; r0 = (b - 4000) * 8; sk = E_;    dk = EP; }
    else if (b < 4512) { src = Wih_b; dst = WihBb; r0 = (b - 4256) * 8; sk = E_;    dk = EP; }
    else if (b < 4768) { src = Whh_f; dst = WhhBf; r0 = (b - 4512) * 8; sk = H_;    dk = H_; }
    else if (b < 5024) { src = Whh_b; dst = WhhBb; r0 = (b - 4768) * 8; sk = H_;    dk = H_; }
    else               { src = S1W;   dst = S1WB;  r0 = (b - 5024) * 8; sk = 2*H_;  dk = 2*H_; }
    const int upr = dk >> 3;            // 8-elem units per row
    for (int u = threadIdx.x; u < 8 * upr; u += 256) {
        const int r  = r0 + u / upr;
        const int c8 = (u % upr) * 8;
        const float* s = &src[(long)r * sk + c8];
        bf16x8 v;
        if (c8 + 8 <= sk) {
            float4 f0 = *(const float4*)&s[0];
            float4 f1 = *(const float4*)&s[4];
            v[0] = (short)f2bf(f0.x); v[1] = (short)f2bf(f0.y);
            v[2] = (short)f2bf(f0.z); v[3] = (short)f2bf(f0.w);
            v[4] = (short)f2bf(f1.x); v[5] = (short)f2bf(f1.y);
            v[6] = (short)f2bf(f1.z); v[7] = (short)f2bf(f1.w);
        } else {
#pragma unroll
            for (int e = 0; e < 8; ++e)
                v[e] = (c8 + e < sk) ? (short)f2bf(s[e]) : (short)0;
        }
        *(bf16x8*)&dst[(long)r * dk + c8] = v;
    }
}

// ---------------------------------------------------------------------------
// K2 v14: v8 publish path VERBATIM; the folded xW work (v13's code, which
// passed correctness) MOVED into the post-store shadow, where the poll's
// ~5k-cycle IC-visibility slack absorbs it:
//   top:  toks(t+1) prefetch (parity double-buffer)
//   poll h(t) -> sync#1 -> xwr=xWs (LDS) -> Whh MFMA -> Gs -> sync#2
//   cell update -> h store              <- publish path identical to v8
//   shadow: stage Aemb(t+1) -> sync#3 -> xW(t+1) GEMM -> publish xWs
// Hazards: toks parity (write pre-sync#1 / read post-sync#2); Aemb reads end
// pre-poll, next write post-sync#2; xWs reads pre-sync#2, writes post-sync#2;
// sync#3 block-uniform. K1 kernel + xf/xb buffers remain deleted.
// ---------------------------------------------------------------------------
__global__ __launch_bounds__(256, 1) void k_recur(
    const int* __restrict__ s1, const int* __restrict__ s2,
    const int* __restrict__ l1, const int* __restrict__ l2,
    const ushort* __restrict__ embB,
    const ushort* __restrict__ WihBf, const ushort* __restrict__ WihBb,
    const float* __restrict__ b_f, const float* __restrict__ b_b,
    ushort* __restrict__ hfB, ushort* __restrict__ hbB,
    const ushort* __restrict__ WhhBf, const ushort* __restrict__ WhhBb,
    const float* __restrict__ s1_c0, const float* __restrict__ s2_c0)
{
    const int bx = blockIdx.x;
    const int s  = bx >> 6;          // stream: 0 fwd, 1 bwd
    const int rb = (bx >> 4) & 3;    // row block of 32
    const int jb = bx & 15;          // j block of 32
    const int r0 = rb * 32, j0 = jb * 32;

    const ushort* Whh  = s ? WhhBb : WhhBf;
    const ushort* WihB = s ? WihBb : WihBf;
    const float*  bias = s ? b_b : b_f;
    ushort* hB = s ? hbB : hfB;

    const int tid = threadIdx.x;
    const int lane = tid & 63;
    const int g = tid >> 6;          // wave = gate (i,f,g,o)
    const int l15 = lane & 15, q8 = (lane >> 4) * 8;

    __shared__ __align__(16) ushort As[32][520];      // h staging (v8 verbatim)
    __shared__ float Gs[4][32][33];                   // gate pre-acts 32 x 32
    __shared__ __align__(16) ushort WihL[128 * 320];  // Wih tile, swizzled
    __shared__ __align__(16) ushort Aemb[32 * 320];   // emb rows, swizzled
    __shared__ __align__(16) ushort xWs[4][32][36];   // xW(t) bf16 (bias incl)
    __shared__ int toks2[2][32];
    __shared__ int Ls[32];

    // Whh fragments resident in registers (v8 verbatim)
    bf16x8 bfr[2][16];
#pragma unroll
    for (int nt = 0; nt < 2; ++nt) {
        const ushort* brow = &Whh[((long)g * H_ + j0 + nt * 16 + l15) * H_];
#pragma unroll
        for (int ks = 0; ks < 16; ++ks)
            bfr[nt][ks] = *(const bf16x8*)&brow[ks * 32 + q8];
    }

    // cell ownership (v8 verbatim)
    const int rr = tid >> 3, jj = (tid & 7) * 4;
    const int rg_ = r0 + rr;
    const int rl  = (rg_ < B_) ? rg_ : rg_ - B_;
    const float* c0p = (rg_ < B_) ? s1_c0 : s2_c0;   // [2][B][H]
    float cst[4];
#pragma unroll
    for (int cc = 0; cc < 4; ++cc)
        cst[cc] = c0p[(long)s * B_ * H_ + (long)rl * H_ + j0 + jj + cc];

    // A staging ids (v8 verbatim)
    const int arow = tid >> 3, aseg = tid & 7;
    const int swz = ((aseg + arow) & 7) * 8;

    // per-lane bias for xW publish (wave g, its two 16-col tiles)
    const float biasv0 = bias[g * H_ + j0 + l15];
    const float biasv1 = bias[g * H_ + j0 + 16 + l15];
    const int cr0 = g * 32 + l15, cr1 = g * 32 + 16 + l15;

    // ---- prologue: lengths + toks(0) ----
    if (tid < 32) {
        int rg = r0 + tid;
        int L = (rg < B_) ? l1[rg] : l2[rg - B_];
        Ls[tid] = L;
        int tt = s ? ((L > 0) ? L - 1 : 0) : 0;
        toks2[0][tid] = (rg < B_) ? s1[rg * T_ + tt] : s2[(rg - B_) * T_ + tt];
    }
    // stage Wih tile -> LDS (swizzled chunks; 128 rows x 320)
    for (int u = tid; u < 5120; u += 256) {
        int cr = u / 40, un = u % 40;
        int grow = (cr >> 5) * H_ + j0 + (cr & 31);
        int pos = (un >> 3) * 64 + ((((un & 7) + cr) & 7) << 3);
        *(bf16x8*)&WihL[cr * 320 + pos] =
            *(const bf16x8*)&WihB[(long)grow * EP + un * 8];
    }
    __syncthreads();
    // stage Aemb(0)
    for (int u = tid; u < 1280; u += 256) {
        int row = u / 40, un = u % 40;
        int pos = (un >> 3) * 64 + ((((un & 7) + row) & 7) << 3);
        *(bf16x8*)&Aemb[row * 320 + pos] =
            *(const bf16x8*)&embB[(long)toks2[0][row] * EP + un * 8];
    }
    __syncthreads();
    // xW(0) GEMM + publish
    {
        f32x4 ax[2][2] = {};
#pragma unroll
        for (int kk = 0; kk < 10; ++kk) {
            int e = kk * 32 + q8;
            int sb = (e >> 6) * 64;
            int ch = (e >> 3) & 7;
            bf16x8 a0 = *(const bf16x8*)&Aemb[l15 * 320 + sb + (((ch + l15) & 7) << 3)];
            bf16x8 a1 = *(const bf16x8*)&Aemb[(16 + l15) * 320 + sb + (((ch + 16 + l15) & 7) << 3)];
            bf16x8 b0 = *(const bf16x8*)&WihL[cr0 * 320 + sb + (((ch + cr0) & 7) << 3)];
            bf16x8 b1 = *(const bf16x8*)&WihL[cr1 * 320 + sb + (((ch + cr1) & 7) << 3)];
            ax[0][0] = MFMA(a0, b0, ax[0][0]);
            ax[0][1] = MFMA(a0, b1, ax[0][1]);
            ax[1][0] = MFMA(a1, b0, ax[1][0]);
            ax[1][1] = MFMA(a1, b1, ax[1][1]);
        }
#pragma unroll
        for (int mt = 0; mt < 2; ++mt)
#pragma unroll
            for (int rgx = 0; rgx < 4; ++rgx) {
                int row = mt * 16 + (lane >> 4) * 4 + rgx;
                xWs[g][row][l15]      = f2bf(ax[mt][0][rgx] + biasv0);
                xWs[g][row][16 + l15] = f2bf(ax[mt][1][rgx] + biasv1);
            }
    }
    // (visibility of xWs(0)/Aemb guaranteed by sync#1 of step 0)

    for (int t = 0; t < T_; ++t) {
        // toks(t+1) prefetch into the OTHER parity slot (read post-sync#2)
        if (t + 1 < T_ && tid < 32) {
            int L = Ls[tid], tq = t + 1;
            int tt = s ? ((tq < L) ? L - 1 - tq : tq) : tq;
            int rg = r0 + tid;
            toks2[(t + 1) & 1][tid] =
                (rg < B_) ? s1[rg * T_ + tt] : s2[(rg - B_) * T_ + tt];
        }

        // h(t): poll the data itself (v8 VERBATIM)
        const ushort* hrow = &hB[((long)(r0 + arow) * TS + t) * H_ + aseg * 8];
        unsigned long long hv[16];
        bool ok;
        do {
#pragma unroll
            for (int i = 0; i < 16; ++i) {
                const unsigned long long* p8 =
                    (const unsigned long long*)(hrow + (i >> 1) * 64 + (i & 1) * 4);
                hv[i] = __hip_atomic_load(p8, __ATOMIC_RELAXED,
                                          __HIP_MEMORY_SCOPE_AGENT);
            }
            ok = true;
#pragma unroll
            for (int i = 0; i < 16; ++i)
                ok = ok && (hv[i] != SENT);
        } while (!ok);

#pragma unroll
        for (int sl = 0; sl < 8; ++sl) {
            uint4 av;
            av.x = (uint)hv[2 * sl];       av.y = (uint)(hv[2 * sl] >> 32);
            av.z = (uint)hv[2 * sl + 1];   av.w = (uint)(hv[2 * sl + 1] >> 32);
            *(uint4*)&As[arow][sl * 64 + swz] = av;
        }
        __syncthreads();   // sync#1

        // xW(t) -> registers (published in last step's shadow)
        uint2 xwr[4];
#pragma unroll
        for (int gg = 0; gg < 4; ++gg)
            xwr[gg] = *(const uint2*)&xWs[gg][rr][jj];

        // Whh MFMA (v8 verbatim)
        f32x4 acc[2][2] = {};
#pragma unroll
        for (int ks = 0; ks < 16; ++ks) {
            const int e  = ks * 32 + q8;
            const int sl = e >> 6;
            const int c  = (e >> 3) & 7;
            bf16x8 a0 = *(const bf16x8*)&As[l15][sl * 64 + (((c + l15) & 7) << 3)];
            bf16x8 a1 = *(const bf16x8*)&As[16 + l15][sl * 64 + (((c + l15) & 7) << 3)];
            acc[0][0] = MFMA(a0, bfr[0][ks], acc[0][0]);
            acc[0][1] = MFMA(a0, bfr[1][ks], acc[0][1]);
            acc[1][0] = MFMA(a1, bfr[0][ks], acc[1][0]);
            acc[1][1] = MFMA(a1, bfr[1][ks], acc[1][1]);
        }

        // publish gate pre-acts (v8 verbatim)
#pragma unroll
        for (int mt = 0; mt < 2; ++mt)
#pragma unroll
            for (int nt = 0; nt < 2; ++nt)
#pragma unroll
                for (int rg2 = 0; rg2 < 4; ++rg2)
                    Gs[g][mt * 16 + (lane >> 4) * 4 + rg2][nt * 16 + l15] =
                        acc[mt][nt][rg2];
        __syncthreads();   // sync#2

        // fused cell update for 4 cols (v8 verbatim, xw from xwr regs)
        ushort hp[4];
#pragma unroll
        for (int cc = 0; cc < 4; ++cc) {
            uint xv0 = (cc < 2) ? xwr[0].x : xwr[0].y;
            uint xv1 = (cc < 2) ? xwr[1].x : xwr[1].y;
            uint xv2 = (cc < 2) ? xwr[2].x : xwr[2].y;
            uint xv3 = (cc < 2) ? xwr[3].x : xwr[3].y;
            int sh = (cc & 1) * 16;
            float gi = Gs[0][rr][jj + cc] + bf2f((ushort)(xv0 >> sh));
            float gf = Gs[1][rr][jj + cc] + bf2f((ushort)(xv1 >> sh));
            float gg = Gs[2][rr][jj + cc] + bf2f((ushort)(xv2 >> sh));
            float go = Gs[3][rr][jj + cc] + bf2f((ushort)(xv3 >> sh));
            cst[cc] = fsig(gf) * cst[cc] + fsig(gi) * ftanh(gg);
            hp[cc] = f2bf(fsig(go) * ftanh(cst[cc]));
        }
        unsigned long long pk = (unsigned long long)hp[0]
                              | ((unsigned long long)hp[1] << 16)
                              | ((unsigned long long)hp[2] << 32)
                              | ((unsigned long long)hp[3] << 48);
        __hip_atomic_store(
            (unsigned long long*)&hB[((long)rg_ * TS + t + 1) * H_ + j0 + jj],
            pk, __ATOMIC_RELAXED, __HIP_MEMORY_SCOPE_AGENT);

        // ---- SHADOW: hidden under the next poll's slack ----
        if (t + 1 < T_) {
            // stage Aemb(t+1)
            for (int u = tid; u < 1280; u += 256) {
                int row = u / 40, un = u % 40;
                int pos = (un >> 3) * 64 + ((((un & 7) + row) & 7) << 3);
                *(bf16x8*)&Aemb[row * 320 + pos] =
                    *(const bf16x8*)&embB[(long)toks2[(t + 1) & 1][row] * EP + un * 8];
            }
            __syncthreads();   // sync#3 (staging writes -> GEMM reads)
            // xW(t+1) GEMM + publish
            f32x4 ax[2][2] = {};
#pragma unroll
            for (int kk = 0; kk < 10; ++kk) {
                int e = kk * 32 + q8;
                int sb = (e >> 6) * 64;
                int ch = (e >> 3) & 7;
                bf16x8 a0 = *(const bf16x8*)&Aemb[l15 * 320 + sb + (((ch + l15) & 7) << 3)];
                bf16x8 a1 = *(const bf16x8*)&Aemb[(16 + l15) * 320 + sb + (((ch + 16 + l15) & 7) << 3)];
                bf16x8 b0 = *(const bf16x8*)&WihL[cr0 * 320 + sb + (((ch + cr0) & 7) << 3)];
                bf16x8 b1 = *(const bf16x8*)&WihL[cr1 * 320 + sb + (((ch + cr1) & 7) << 3)];
                ax[0][0] = MFMA(a0, b0, ax[0][0]);
                ax[0][1] = MFMA(a0, b1, ax[0][1]);
                ax[1][0] = MFMA(a1, b0, ax[1][0]);
                ax[1][1] = MFMA(a1, b1, ax[1][1]);
            }
#pragma unroll
            for (int mt = 0; mt < 2; ++mt)
#pragma unroll
                for (int rgx = 0; rgx < 4; ++rgx) {
                    int row = mt * 16 + (lane >> 4) * 4 + rgx;
                    xWs[g][row][l15]      = f2bf(ax[mt][0][rgx] + biasv0);
                    xWs[g][row][16 + l15] = f2bf(ax[mt][1][rgx] + biasv1);
                }
            // visibility of xWs(t+1) to readers: next sync#1
        }
    }
}

// ---------------------------------------------------------------------------
// K3 FUSED (round-5/6 verbatim, passed): U acc-resident, scores via shfl
// reduce + LDS atomicAdd, masked softmax, pool.
// ---------------------------------------------------------------------------
__global__ __launch_bounds__(256) void k_attn_fused(
    const ushort* __restrict__ hfB, const ushort* __restrict__ hbB,
    const int* __restrict__ l1, const int* __restrict__ l2,
    const ushort* __restrict__ S1WB, const float* __restrict__ S2W,
    float* __restrict__ pooled)
{
    const int r = blockIdx.x;
    const int L = (r < B_) ? l1[r] : l2[r - B_];
    const int tid = threadIdx.x;
    const int lane = tid & 63, w = tid >> 6;
    const int wm = w & 1, wn = w >> 1;
    const int l15 = lane & 15, q8 = (lane >> 4) * 8;

    __shared__ __align__(16) ushort As[128][72];   // 128 t-rows x 64 k
    __shared__ __align__(16) ushort Bs[256][72];   // 256 c-rows x 64 k
    __shared__ float sc[T_];
    __shared__ float att[T_];

    if (tid < T_) sc[tid] = 0.0f;

    f32x4 acc[4][8] = {};

    for (int k0 = 0; k0 < 2 * H_; k0 += 64) {
#pragma unroll
        for (int p = 0; p < 4; ++p) {   // A: 128 rows x 64 k
            int u = tid + p * 256;
            int row = u >> 3, seg = u & 7;
            int k = k0 + seg * 8;
            long idx;
            const ushort* src;
            if (k0 < H_) {
                src = hfB; idx = ((long)r * TS + row + 1) * H_ + k;
            } else {
                int tt = (row < L) ? (L - 1 - row) : row;
                src = hbB; idx = ((long)r * TS + tt + 1) * H_ + (k - H_);
            }
            *(uint4*)&As[row][seg * 8] = *(const uint4*)&src[idx];
        }
#pragma unroll
        for (int p = 0; p < 8; ++p) {   // B: 256 c-rows x 64 k
            int u = tid + p * 256;
            int row = u >> 3, seg = u & 7;
            *(uint4*)&Bs[row][seg * 8] =
                *(const uint4*)&S1WB[(long)row * (2 * H_) + k0 + seg * 8];
        }
        __syncthreads();
#pragma unroll
        for (int ks = 0; ks < 2; ++ks) {
            bf16x8 af[4], bfr[8];
#pragma unroll
            for (int mt = 0; mt < 4; ++mt)
                af[mt] = *(const bf16x8*)&As[wm * 64 + mt * 16 + l15][ks * 32 + q8];
#pragma unroll
            for (int nt = 0; nt < 8; ++nt)
                bfr[nt] = *(const bf16x8*)&Bs[wn * 128 + nt * 16 + l15][ks * 32 + q8];
#pragma unroll
            for (int mt = 0; mt < 4; ++mt)
#pragma unroll
                for (int nt = 0; nt < 8; ++nt)
                    acc[mt][nt] = MFMA(af[mt], bfr[nt], acc[mt][nt]);
        }
        __syncthreads();
    }

    float s2r[8];
#pragma unroll
    for (int nt = 0; nt < 8; ++nt)
        s2r[nt] = S2W[wn * 128 + nt * 16 + l15];
#pragma unroll
    for (int mt = 0; mt < 4; ++mt)
#pragma unroll
        for (int rg = 0; rg < 4; ++rg) {
            float v = 0.0f;
#pragma unroll
            for (int nt = 0; nt < 8; ++nt)
                v += ftanh(acc[mt][nt][rg]) * s2r[nt];
            v += __shfl_xor(v, 1);
            v += __shfl_xor(v, 2);
            v += __shfl_xor(v, 4);
            v += __shfl_xor(v, 8);
            if (l15 == 0)
                atomicAdd(&sc[wm * 64 + mt * 16 + (lane >> 4) * 4 + rg], v);
        }
    __syncthreads();

    float mx = -1e30f;
    for (int tt = 0; tt < L; ++tt) mx = fmaxf(mx, sc[tt]);
    __syncthreads();
    if (tid < T_) att[tid] = (tid < L) ? __expf(sc[tid] - mx) : 0.0f;
    __syncthreads();
    float sum = 0.0f;
    for (int tt = 0; tt < L; ++tt) sum += att[tt];
    float inv = 1.0f / sum;

    for (int p = tid; p < 512; p += 256) {
        float a0 = 0.0f, a1 = 0.0f;
        if (p < 256) {
            int d = p * 2;
            for (int tt = 0; tt < L; ++tt) {
                uint hv = *(const uint*)&hfB[((long)r * TS + tt + 1) * H_ + d];
                a0 += att[tt] * bf2f((ushort)(hv & 0xffff));
                a1 += att[tt] * bf2f((ushort)(hv >> 16));
            }
            pooled[(long)r * (2 * H_) + d]     = a0 * inv;
            pooled[(long)r * (2 * H_) + d + 1] = a1 * inv;
        } else {
            int d = (p - 256) * 2;
            for (int tt = 0; tt < L; ++tt) {
                uint hv = *(const uint*)&hbB[((long)r * TS + (L - tt)) * H_ + d];
                a0 += att[tt] * bf2f((ushort)(hv & 0xffff));
                a1 += att[tt] * bf2f((ushort)(hv >> 16));
            }
            pooled[(long)r * (2 * H_) + H_ + d]     = a0 * inv;
            pooled[(long)r * (2 * H_) + H_ + d + 1] = a1 * inv;
        }
    }
}

// ---------------------------------------------------------------------------
// K4a: om[b][mm] = merged[b] . mlpW[mm] + mlpb[mm] (unchanged).
// ---------------------------------------------------------------------------
__global__ __launch_bounds__(256) void k_mlp1(
    const float* __restrict__ pooled,
    const float* __restrict__ mlpW, const float* __restrict__ mlpb,
    float* __restrict__ om)
{
    const int mg = blockIdx.x;      // 0..7
    const int b  = blockIdx.y;      // 0..63
    const int tid = threadIdx.x;
    const int lane = tid & 63, w = tid >> 6;

    __shared__ __align__(16) float sm[2048];

#pragma unroll
    for (int it = 0; it < 8; ++it) {
        int d = tid + it * 256;
        float v;
        if (d < 1024) {
            v = pooled[(long)b * 1024 + d] + pooled[(long)(B_ + b) * 1024 + d];
        } else {
            int dd = d - 1024;
            float x = pooled[(long)b * 1024 + dd] - pooled[(long)(B_ + b) * 1024 + dd];
            v = x * x;
        }
        sm[d] = v;
    }
    __syncthreads();

    for (int i = 0; i < 16; ++i) {
        int mm = mg * 64 + w * 16 + i;
        const float* wrow = &mlpW[(long)mm * 2048];
        float ax = 0.f, ay = 0.f, az = 0.f, aw = 0.f;
#pragma unroll
        for (int it = 0; it < 8; ++it) {
            int k = it * 256 + lane * 4;
            float4 wv = *(const float4*)&wrow[k];
            float4 sv = *(const float4*)&sm[k];
            ax += wv.x * sv.x; ay += wv.y * sv.y;
            az += wv.z * sv.z; aw += wv.w * sv.w;
        }
        float ssum = (ax + ay) + (az + aw);
        for (int off = 32; off; off >>= 1) ssum += __shfl_down(ssum, off);
        if (lane == 0) om[(long)b * M_ + mm] = ssum + mlpb[mm];
    }
}

// K4b: out[b] = sigmoid(om[b] . outW + outb)   (CLS = 1)
__global__ __launch_bounds__(256) void k_final(
    const float* __restrict__ om,
    const float* __restrict__ outW, const float* __restrict__ outb,
    float* __restrict__ out)
{
    const int b = blockIdx.x;
    const int tid = threadIdx.x;
    __shared__ float red[256];
    float p = om[(long)b * M_ + tid] * outW[tid]
            + om[(long)b * M_ + 256 + tid] * outW[256 + tid];
    red[tid] = p;
    __syncthreads();
    for (int off = 128; off > 0; off >>= 1) {
        if (tid < off) red[tid] += red[tid + off];
        __syncthreads();
    }
    if (tid == 0) out[b] = 1.0f / (1.0f + __expf(-(red[0] + outb[0])));
}

// ---------------------------------------------------------------------------
extern "C" void kernel_launch(void* const* d_in, const int* in_sizes, int n_in,
                              void* d_out, int out_size, void* d_ws, size_t ws_size,
                              hipStream_t stream)
{
    const int*   s1    = (const int*)d_in[0];
    const int*   s2    = (const int*)d_in[1];
    const int*   l1    = (const int*)d_in[2];
    const int*   l2    = (const int*)d_in[3];
    const float* s1_h0 = (const float*)d_in[4];
    const float* s1_c0 = (const float*)d_in[5];
    const float* s2_h0 = (const float*)d_in[6];
    const float* s2_c0 = (const float*)d_in[7];
    const float* emb   = (const float*)d_in[8];
    const float* Wih_f = (const float*)d_in[9];
    const float* Whh_f = (const float*)d_in[10];
    const float* b_f   = (const float*)d_in[11];
    const float* Wih_b = (const float*)d_in[12];
    const float* Whh_b = (const float*)d_in[13];
    const float* b_b   = (const float*)d_in[14];
    const float* S1W   = (const float*)d_in[15];
    const float* S2W   = (const float*)d_in[16];
    const float* mlpW  = (const float*)d_in[17];
    const float* mlpb  = (const float*)d_in[18];
    const float* outW  = (const float*)d_in[19];
    const float* outb  = (const float*)d_in[20];
    float* out = (float*)d_out;

    // Workspace carve (all 16B-aligned); xf/xb eliminated by the K1 fusion.
    ushort* p16 = (ushort*)d_ws;
    ushort* embB  = p16;  p16 += (long)32000 * EP;
    ushort* WihBf = p16;  p16 += (long)G4 * EP;
    ushort* WihBb = p16;  p16 += (long)G4 * EP;
    ushort* WhhBf = p16;  p16 += (long)G4 * H_;
    ushort* WhhBb = p16;  p16 += (long)G4 * H_;
    ushort* S1WB  = p16;  p16 += (long)C_ * 2 * H_;
    ushort* hfB   = p16;  p16 += (long)R_ * TS * H_;
    ushort* hbB   = p16;  p16 += (long)R_ * TS * H_;
    float* pf = (float*)p16;
    float* pooled = pf;   pf += (long)R_ * 2 * H_;
    float* om     = pf;   pf += (long)B_ * M_;

    // sentinel-fill h arrays (0xFF bytes -> every 8B chunk = SENT); the
    // cvt_all init-role then writes real h0 into slot 0. hfB/hbB contiguous.
    hipMemsetAsync(hfB, 0xFF, (size_t)2 * R_ * TS * H_ * sizeof(ushort), stream);

    // P0 v2: vectorized weight conversion + h0 init
    k_cvt_all<<<5184, 256, 0, stream>>>(emb, Wih_f, Wih_b, Whh_f, Whh_b, S1W,
                                        s1_h0, s2_h0,
                                        embB, WihBf, WihBb, WhhBf, WhhBb, S1WB,
                                        hfB, hbB);

    // K2 v14: recurrence with xW GEMM in the post-store shadow (K1 deleted)
    k_recur<<<NB, 256, 0, stream>>>(s1, s2, l1, l2, embB, WihBf, WihBb,
                                    b_f, b_b, hfB, hbB, WhhBf, WhhBb,
                                    s1_c0, s2_c0);

    // K3: fused attention (GEMM + scores + softmax + pool)
    k_attn_fused<<<R_, 256, 0, stream>>>(hfB, hbB, l1, l2, S1WB, S2W, pooled);

    // K4: MLP head
    k_mlp1<<<dim3(8, B_), 256, 0, stream>>>(pooled, mlpW, mlpb, om);
    k_final<<<B_, 256, 0, stream>>>(om, outW, outb, out);
}

// Round 9
// 788.083 us; speedup vs baseline: 1.2717x; 1.2061x over previous
//
#include <hip/hip_runtime.h>
#include <hip/hip_bf16.h>

// Problem constants (fixed by the reference)
#define B_  64
#define T_  128
#define E_  300
#define EP  320     // E padded to multiple of 32 for MFMA K-loop
#define H_  512
#define G4  2048    // 4*H
#define R_  128     // 2*B (s1+s2 batched; shared LSTM weights)
#define C_  256
#define M_  512
#define TS  (T_ + 1)  // h time slots: slot 0 = h0, slot t+1 = h(t)
#define NB  128     // persistent-kernel grid: 2 streams x 4 rowblocks x 16 jblocks
#define SENT 0xFFFFFFFFFFFFFFFFULL   // 4x bf16 NaN — unreachable by real h

typedef short bf16x8 __attribute__((ext_vector_type(8)));
typedef float f32x4  __attribute__((ext_vector_type(4)));
#define MFMA(a, b, c) __builtin_amdgcn_mfma_f32_16x16x32_bf16((a), (b), (c), 0, 0, 0)

__device__ __forceinline__ float fsig(float x) { return 1.0f / (1.0f + __expf(-x)); }
__device__ __forceinline__ float ftanh(float x) {
    float a = fminf(fabsf(x), 15.0f);
    float e = __expf(2.0f * a);
    return copysignf((e - 1.0f) / (e + 1.0f), x);
}
__device__ __forceinline__ ushort f2bf(float f) {
    __hip_bfloat16 h = __float2bfloat16(f);
    return *reinterpret_cast<ushort*>(&h);
}
__device__ __forceinline__ float bf2f(ushort u) {
    __hip_bfloat16 h = *reinterpret_cast<__hip_bfloat16*>(&u);
    return __bfloat162float(h);
}

// ---------------------------------------------------------------------------
// P0 v2: VECTORIZED f32 -> bf16 conversion (round-6 verbatim).
// ---------------------------------------------------------------------------
__global__ __launch_bounds__(256) void k_cvt_all(
    const float* __restrict__ emb,
    const float* __restrict__ Wih_f, const float* __restrict__ Wih_b,
    const float* __restrict__ Whh_f, const float* __restrict__ Whh_b,
    const float* __restrict__ S1W,
    const float* __restrict__ s1_h0, const float* __restrict__ s2_h0,
    ushort* __restrict__ embB,
    ushort* __restrict__ WihBf, ushort* __restrict__ WihBb,
    ushort* __restrict__ WhhBf, ushort* __restrict__ WhhBb,
    ushort* __restrict__ S1WB,
    ushort* __restrict__ hfB, ushort* __restrict__ hbB)
{
    const int b = blockIdx.x;
    if (b >= 5056) {   // h0 init role: 128 blocks, one r each
        const int r = b - 5056;                      // 0..127
        const int rl = (r < B_) ? r : r - B_;
        const float* h0 = (r < B_) ? s1_h0 : s2_h0;  // [2][B][H]
        for (int u = threadIdx.x; u < 128; u += 256) {
            const int which = u >> 6;                // 0: fwd/hf, 1: bwd/hb
            const int c8 = (u & 63) * 8;
            const float* s = h0 + (long)which * B_ * H_ + (long)rl * H_ + c8;
            ushort* d = (which ? hbB : hfB) + (long)r * TS * H_ + c8;
            float4 f0 = *(const float4*)&s[0];
            float4 f1 = *(const float4*)&s[4];
            bf16x8 v;
            v[0] = (short)f2bf(f0.x); v[1] = (short)f2bf(f0.y);
            v[2] = (short)f2bf(f0.z); v[3] = (short)f2bf(f0.w);
            v[4] = (short)f2bf(f1.x); v[5] = (short)f2bf(f1.y);
            v[6] = (short)f2bf(f1.z); v[7] = (short)f2bf(f1.w);
            *(bf16x8*)d = v;
        }
        return;
    }
    const float* src; ushort* dst; int r0, sk, dk;
    if (b < 4000)      { src = emb;   dst = embB;  r0 = b * 8;          sk = E_;    dk = EP; }
    else if (b < 4256) { src = Wih_f; dst = WihBf; r0 = (b - 4000) * 8; sk = E_;    dk = EP; }
    else if (b < 4512) { src = Wih_b; dst = WihBb; r0 = (b - 4256) * 8; sk = E_;    dk = EP; }
    else if (b < 4768) { src = Whh_f; dst = WhhBf; r0 = (b - 4512) * 8; sk = H_;    dk = H_; }
    else if (b < 5024) { src = Whh_b; dst = WhhBb; r0 = (b - 4768) * 8; sk = H_;    dk = H_; }
    else               { src = S1W;   dst = S1WB;  r0 = (b - 5024) * 8; sk = 2*H_;  dk = 2*H_; }
    const int upr = dk >> 3;            // 8-elem units per row
    for (int u = threadIdx.x; u < 8 * upr; u += 256) {
        const int r  = r0 + u / upr;
        const int c8 = (u % upr) * 8;
        const float* s = &src[(long)r * sk + c8];
        bf16x8 v;
        if (c8 + 8 <= sk) {
            float4 f0 = *(const float4*)&s[0];
            float4 f1 = *(const float4*)&s[4];
            v[0] = (short)f2bf(f0.x); v[1] = (short)f2bf(f0.y);
            v[2] = (short)f2bf(f0.z); v[3] = (short)f2bf(f0.w);
            v[4] = (short)f2bf(f1.x); v[5] = (short)f2bf(f1.y);
            v[6] = (short)f2bf(f1.z); v[7] = (short)f2bf(f1.w);
        } else {
#pragma unroll
            for (int e = 0; e < 8; ++e)
                v[e] = (c8 + e < sk) ? (short)f2bf(s[e]) : (short)0;
        }
        *(bf16x8*)&dst[(long)r * dk + c8] = v;
    }
}

// ---------------------------------------------------------------------------
// K1 v2: embedding gather + input GEMM via bf16 MFMA (round-6 verbatim).
// Tile 64x256, BK=64; L<=t0 early-exit; shfl_xor(1) paired 4B stores.
// ---------------------------------------------------------------------------
__global__ __launch_bounds__(256) void k_embed_mfma(
    const int* __restrict__ s1, const int* __restrict__ s2,
    const int* __restrict__ l1, const int* __restrict__ l2,
    const ushort* __restrict__ embB,
    const ushort* __restrict__ WihBf, const ushort* __restrict__ WihBb,
    const float* __restrict__ b_f, const float* __restrict__ b_b,
    ushort* __restrict__ xf, ushort* __restrict__ xb)
{
    const int dir = blockIdx.z;
    const int r   = blockIdx.y >> 1;
    const int t0  = (blockIdx.y & 1) * 64;
    const int N0  = blockIdx.x * 256;
    const int L   = (r < B_) ? l1[r] : l2[r - B_];
    if (L <= t0) return;

    const int tid = threadIdx.x;
    const int lane = tid & 63, w = tid >> 6;
    const int wm = w & 1, wn = w >> 1;
    const int l15 = lane & 15, q8 = (lane >> 4) * 8;

    __shared__ int toks[64];
    __shared__ __align__(16) ushort As[64][72];
    __shared__ __align__(16) ushort Bs[256][72];

    if (tid < 64) {
        int t  = t0 + tid;
        int tt = dir ? ((t < L) ? (L - 1 - t) : t) : t;
        toks[tid] = (r < B_) ? s1[r * T_ + tt] : s2[(r - B_) * T_ + tt];
    }
    __syncthreads();

    const ushort* Wih  = dir ? WihBb : WihBf;
    const float*  bias = dir ? b_b : b_f;

    f32x4 acc[2][8] = {};

    for (int k0 = 0; k0 < EP; k0 += 64) {
#pragma unroll
        for (int p = 0; p < 2; ++p) {   // A: 64 rows x 64 k
            int u = tid + p * 256;
            int row = u >> 3, seg = u & 7;
            *(uint4*)&As[row][seg * 8] =
                *(const uint4*)&embB[(long)toks[row] * EP + k0 + seg * 8];
        }
#pragma unroll
        for (int p = 0; p < 8; ++p) {   // B: 256 cols x 64 k
            int u = tid + p * 256;
            int row = u >> 3, seg = u & 7;
            *(uint4*)&Bs[row][seg * 8] =
                *(const uint4*)&Wih[(long)(N0 + row) * EP + k0 + seg * 8];
        }
        __syncthreads();
#pragma unroll
        for (int ks = 0; ks < 2; ++ks) {
            bf16x8 af[2], bfr[8];
#pragma unroll
            for (int mt = 0; mt < 2; ++mt)
                af[mt] = *(const bf16x8*)&As[wm * 32 + mt * 16 + l15][ks * 32 + q8];
#pragma unroll
            for (int nt = 0; nt < 8; ++nt)
                bfr[nt] = *(const bf16x8*)&Bs[wn * 128 + nt * 16 + l15][ks * 32 + q8];
#pragma unroll
            for (int mt = 0; mt < 2; ++mt)
#pragma unroll
                for (int nt = 0; nt < 8; ++nt)
                    acc[mt][nt] = MFMA(af[mt], bfr[nt], acc[mt][nt]);
        }
        __syncthreads();
    }

    ushort* xout = dir ? xb : xf;
#pragma unroll
    for (int mt = 0; mt < 2; ++mt) {
        int m = r * T_ + t0 + wm * 32 + mt * 16 + (lane >> 4) * 4;
#pragma unroll
        for (int nt = 0; nt < 8; ++nt) {
            int col = N0 + wn * 128 + nt * 16 + l15;
            float bv = bias[col];
#pragma unroll
            for (int rg = 0; rg < 4; ++rg) {
                uint v = f2bf(acc[mt][nt][rg] + bv);
                uint pv = (uint)__shfl_xor((int)v, 1);
                if (!(lane & 1))
                    *(uint*)&xout[(long)(m + rg) * G4 + col] = v | (pv << 16);
            }
        }
    }
}

// ---------------------------------------------------------------------------
// K2 v15: v8 VERBATIM except the poll loop -> TWO-PHASE DENSE POLL.
// Theory: v8's step = 8500cy but busy+latency model accounts for ~3500cy;
// the remainder is IC saturation by the reload-all poll itself (128 blocks x
// 32KB per ~800cy pass ~= 12 TB/s of agent-load traffic at the coherence
// point, queuing both polls and store drains). v12's accept-once cut traffic
// but via per-chunk masks -> divergent serialized loads (worse). v15 keeps
// every pass DENSE and UNIFORM: spin on a fixed half of the chunks (8
// unconditional 8B loads/pass), then verify the other fixed half (usually 1
// pass: a producer wave's stores land together). Halves steady-state poll
// bandwidth with no masks / sleeps / fences. Everything else is v8 verbatim.
// ---------------------------------------------------------------------------
__global__ __launch_bounds__(256) void k_recur(
    const ushort* __restrict__ xf, const ushort* __restrict__ xb,
    ushort* __restrict__ hfB, ushort* __restrict__ hbB,
    const ushort* __restrict__ WhhBf, const ushort* __restrict__ WhhBb,
    const float* __restrict__ s1_c0, const float* __restrict__ s2_c0)
{
    const int bx = blockIdx.x;
    const int s  = bx >> 6;          // stream: 0 fwd, 1 bwd
    const int rb = (bx >> 4) & 3;    // row block of 32
    const int jb = bx & 15;          // j block of 32
    const int r0 = rb * 32, j0 = jb * 32;

    const ushort* xW  = s ? xb : xf;
    const ushort* Whh = s ? WhhBb : WhhBf;
    ushort* hB = s ? hbB : hfB;

    const int tid = threadIdx.x;
    const int lane = tid & 63;
    const int g = tid >> 6;          // wave = gate (i,f,g,o)
    const int l15 = lane & 15, q8 = (lane >> 4) * 8;

    __shared__ __align__(16) ushort As[32][520];   // 32 rows x 512 k, swizzled chunks
    __shared__ float Gs[4][32][33];                // gate pre-acts 32 x 32

    // Whh fragments resident in registers: wave g, 32 cols (2 n-tiles), K=512
    bf16x8 bfr[2][16];
#pragma unroll
    for (int nt = 0; nt < 2; ++nt) {
        const ushort* brow = &Whh[((long)g * H_ + j0 + nt * 16 + l15) * H_];
#pragma unroll
        for (int ks = 0; ks < 16; ++ks)
            bfr[nt][ks] = *(const bf16x8*)&brow[ks * 32 + q8];
    }

    // cell ownership: thread -> (row rr, 4 cols at jj)
    const int rr = tid >> 3, jj = (tid & 7) * 4;
    const int rg_ = r0 + rr;
    const int rl  = (rg_ < B_) ? rg_ : rg_ - B_;
    const float* c0p = (rg_ < B_) ? s1_c0 : s2_c0;   // [2][B][H]
    float cst[4];
#pragma unroll
    for (int cc = 0; cc < 4; ++cc)
        cst[cc] = c0p[(long)s * B_ * H_ + (long)rl * H_ + j0 + jj + cc];

    // A staging: thread -> (row arow, chunk aseg); chunk placed at (aseg+arow)&7
    const int arow = tid >> 3, aseg = tid & 7;
    const int swz = ((aseg + arow) & 7) * 8;

    for (int t = 0; t < T_; ++t) {
        // xW gate pre-activations (4 cols x 4 gates) — issued before the
        // h poll so their latency hides under the wait
        uint2 xw[4];
        const long xbase = ((long)rg_ * T_ + t) * G4 + j0 + jj;
#pragma unroll
        for (int gg = 0; gg < 4; ++gg)
            xw[gg] = *(const uint2*)&xW[xbase + gg * H_];

        // h(t): TWO-PHASE dense poll. Phase A: even chunks (8 x 8B,
        // unconditional). Phase B: odd chunks (8 x 8B). Both loops uniform.
        const ushort* hrow = &hB[((long)(r0 + arow) * TS + t) * H_ + aseg * 8];
        unsigned long long hv[16];
        bool ok;
        do {
#pragma unroll
            for (int i = 0; i < 16; i += 2) {
                const unsigned long long* p8 =
                    (const unsigned long long*)(hrow + (i >> 1) * 64);
                hv[i] = __hip_atomic_load(p8, __ATOMIC_RELAXED,
                                          __HIP_MEMORY_SCOPE_AGENT);
            }
            ok = true;
#pragma unroll
            for (int i = 0; i < 16; i += 2)
                ok = ok && (hv[i] != SENT);
        } while (!ok);
        do {
#pragma unroll
            for (int i = 1; i < 16; i += 2) {
                const unsigned long long* p8 =
                    (const unsigned long long*)(hrow + (i >> 1) * 64 + 4);
                hv[i] = __hip_atomic_load(p8, __ATOMIC_RELAXED,
                                          __HIP_MEMORY_SCOPE_AGENT);
            }
            ok = true;
#pragma unroll
            for (int i = 1; i < 16; i += 2)
                ok = ok && (hv[i] != SENT);
        } while (!ok);

#pragma unroll
        for (int sl = 0; sl < 8; ++sl) {
            uint4 av;
            av.x = (uint)hv[2 * sl];       av.y = (uint)(hv[2 * sl] >> 32);
            av.z = (uint)hv[2 * sl + 1];   av.w = (uint)(hv[2 * sl + 1] >> 32);
            *(uint4*)&As[arow][sl * 64 + swz] = av;
        }
        __syncthreads();

        f32x4 acc[2][2] = {};   // [mtile][ntile]
#pragma unroll
        for (int ks = 0; ks < 16; ++ks) {
            const int e  = ks * 32 + q8;
            const int sl = e >> 6;
            const int c  = (e >> 3) & 7;
            bf16x8 a0 = *(const bf16x8*)&As[l15][sl * 64 + (((c + l15) & 7) << 3)];
            bf16x8 a1 = *(const bf16x8*)&As[16 + l15][sl * 64 + (((c + l15) & 7) << 3)];
            acc[0][0] = MFMA(a0, bfr[0][ks], acc[0][0]);
            acc[0][1] = MFMA(a0, bfr[1][ks], acc[0][1]);
            acc[1][0] = MFMA(a1, bfr[0][ks], acc[1][0]);
            acc[1][1] = MFMA(a1, bfr[1][ks], acc[1][1]);
        }

        // publish gate pre-acts (C layout: col=lane&15, row=(lane>>4)*4+rg)
#pragma unroll
        for (int mt = 0; mt < 2; ++mt)
#pragma unroll
            for (int nt = 0; nt < 2; ++nt)
#pragma unroll
                for (int rg2 = 0; rg2 < 4; ++rg2)
                    Gs[g][mt * 16 + (lane >> 4) * 4 + rg2][nt * 16 + l15] =
                        acc[mt][nt][rg2];
        __syncthreads();

        // fused cell update for 4 cols
        ushort hp[4];
#pragma unroll
        for (int cc = 0; cc < 4; ++cc) {
            uint xv0 = (cc < 2) ? xw[0].x : xw[0].y;
            uint xv1 = (cc < 2) ? xw[1].x : xw[1].y;
            uint xv2 = (cc < 2) ? xw[2].x : xw[2].y;
            uint xv3 = (cc < 2) ? xw[3].x : xw[3].y;
            int sh = (cc & 1) * 16;
            float gi = Gs[0][rr][jj + cc] + bf2f((ushort)(xv0 >> sh));
            float gf = Gs[1][rr][jj + cc] + bf2f((ushort)(xv1 >> sh));
            float gg = Gs[2][rr][jj + cc] + bf2f((ushort)(xv2 >> sh));
            float go = Gs[3][rr][jj + cc] + bf2f((ushort)(xv3 >> sh));
            cst[cc] = fsig(gf) * cst[cc] + fsig(gi) * ftanh(gg);
            hp[cc] = f2bf(fsig(go) * ftanh(cst[cc]));
        }
        unsigned long long pk = (unsigned long long)hp[0]
                              | ((unsigned long long)hp[1] << 16)
                              | ((unsigned long long)hp[2] << 32)
                              | ((unsigned long long)hp[3] << 48);
        __hip_atomic_store(
            (unsigned long long*)&hB[((long)rg_ * TS + t + 1) * H_ + j0 + jj],
            pk, __ATOMIC_RELAXED, __HIP_MEMORY_SCOPE_AGENT);
    }
}

// ---------------------------------------------------------------------------
// K3 FUSED (round-6 verbatim, passed): U acc-resident, scores via shfl
// reduce + LDS atomicAdd, masked softmax, pool.
// ---------------------------------------------------------------------------
__global__ __launch_bounds__(256) void k_attn_fused(
    const ushort* __restrict__ hfB, const ushort* __restrict__ hbB,
    const int* __restrict__ l1, const int* __restrict__ l2,
    const ushort* __restrict__ S1WB, const float* __restrict__ S2W,
    float* __restrict__ pooled)
{
    const int r = blockIdx.x;
    const int L = (r < B_) ? l1[r] : l2[r - B_];
    const int tid = threadIdx.x;
    const int lane = tid & 63, w = tid >> 6;
    const int wm = w & 1, wn = w >> 1;
    const int l15 = lane & 15, q8 = (lane >> 4) * 8;

    __shared__ __align__(16) ushort As[128][72];   // 128 t-rows x 64 k
    __shared__ __align__(16) ushort Bs[256][72];   // 256 c-rows x 64 k
    __shared__ float sc[T_];
    __shared__ float att[T_];

    if (tid < T_) sc[tid] = 0.0f;

    f32x4 acc[4][8] = {};

    for (int k0 = 0; k0 < 2 * H_; k0 += 64) {
#pragma unroll
        for (int p = 0; p < 4; ++p) {   // A: 128 rows x 64 k
            int u = tid + p * 256;
            int row = u >> 3, seg = u & 7;
            int k = k0 + seg * 8;
            long idx;
            const ushort* src;
            if (k0 < H_) {
                src = hfB; idx = ((long)r * TS + row + 1) * H_ + k;
            } else {
                int tt = (row < L) ? (L - 1 - row) : row;
                src = hbB; idx = ((long)r * TS + tt + 1) * H_ + (k - H_);
            }
            *(uint4*)&As[row][seg * 8] = *(const uint4*)&src[idx];
        }
#pragma unroll
        for (int p = 0; p < 8; ++p) {   // B: 256 c-rows x 64 k
            int u = tid + p * 256;
            int row = u >> 3, seg = u & 7;
            *(uint4*)&Bs[row][seg * 8] =
                *(const uint4*)&S1WB[(long)row * (2 * H_) + k0 + seg * 8];
        }
        __syncthreads();
#pragma unroll
        for (int ks = 0; ks < 2; ++ks) {
            bf16x8 af[4], bfr[8];
#pragma unroll
            for (int mt = 0; mt < 4; ++mt)
                af[mt] = *(const bf16x8*)&As[wm * 64 + mt * 16 + l15][ks * 32 + q8];
#pragma unroll
            for (int nt = 0; nt < 8; ++nt)
                bfr[nt] = *(const bf16x8*)&Bs[wn * 128 + nt * 16 + l15][ks * 32 + q8];
#pragma unroll
            for (int mt = 0; mt < 4; ++mt)
#pragma unroll
                for (int nt = 0; nt < 8; ++nt)
                    acc[mt][nt] = MFMA(af[mt], bfr[nt], acc[mt][nt]);
        }
        __syncthreads();
    }

    float s2r[8];
#pragma unroll
    for (int nt = 0; nt < 8; ++nt)
        s2r[nt] = S2W[wn * 128 + nt * 16 + l15];
#pragma unroll
    for (int mt = 0; mt < 4; ++mt)
#pragma unroll
        for (int rg = 0; rg < 4; ++rg) {
            float v = 0.0f;
#pragma unroll
            for (int nt = 0; nt < 8; ++nt)
                v += ftanh(acc[mt][nt][rg]) * s2r[nt];
            v += __shfl_xor(v, 1);
            v += __shfl_xor(v, 2);
            v += __shfl_xor(v, 4);
            v += __shfl_xor(v, 8);
            if (l15 == 0)
                atomicAdd(&sc[wm * 64 + mt * 16 + (lane >> 4) * 4 + rg], v);
        }
    __syncthreads();

    float mx = -1e30f;
    for (int tt = 0; tt < L; ++tt) mx = fmaxf(mx, sc[tt]);
    __syncthreads();
    if (tid < T_) att[tid] = (tid < L) ? __expf(sc[tid] - mx) : 0.0f;
    __syncthreads();
    float sum = 0.0f;
    for (int tt = 0; tt < L; ++tt) sum += att[tt];
    float inv = 1.0f / sum;

    for (int p = tid; p < 512; p += 256) {
        float a0 = 0.0f, a1 = 0.0f;
        if (p < 256) {
            int d = p * 2;
            for (int tt = 0; tt < L; ++tt) {
                uint hv = *(const uint*)&hfB[((long)r * TS + tt + 1) * H_ + d];
                a0 += att[tt] * bf2f((ushort)(hv & 0xffff));
                a1 += att[tt] * bf2f((ushort)(hv >> 16));
            }
            pooled[(long)r * (2 * H_) + d]     = a0 * inv;
            pooled[(long)r * (2 * H_) + d + 1] = a1 * inv;
        } else {
            int d = (p - 256) * 2;
            for (int tt = 0; tt < L; ++tt) {
                uint hv = *(const uint*)&hbB[((long)r * TS + (L - tt)) * H_ + d];
                a0 += att[tt] * bf2f((ushort)(hv & 0xffff));
                a1 += att[tt] * bf2f((ushort)(hv >> 16));
            }
            pooled[(long)r * (2 * H_) + H_ + d]     = a0 * inv;
            pooled[(long)r * (2 * H_) + H_ + d + 1] = a1 * inv;
        }
    }
}

// ---------------------------------------------------------------------------
// K4a: om[b][mm] = merged[b] . mlpW[mm] + mlpb[mm] (unchanged).
// ---------------------------------------------------------------------------
__global__ __launch_bounds__(256) void k_mlp1(
    const float* __restrict__ pooled,
    const float* __restrict__ mlpW, const float* __restrict__ mlpb,
    float* __restrict__ om)
{
    const int mg = blockIdx.x;      // 0..7
    const int b  = blockIdx.y;      // 0..63
    const int tid = threadIdx.x;
    const int lane = tid & 63, w = tid >> 6;

    __shared__ __align__(16) float sm[2048];

#pragma unroll
    for (int it = 0; it < 8; ++it) {
        int d = tid + it * 256;
        float v;
        if (d < 1024) {
            v = pooled[(long)b * 1024 + d] + pooled[(long)(B_ + b) * 1024 + d];
        } else {
            int dd = d - 1024;
            float x = pooled[(long)b * 1024 + dd] - pooled[(long)(B_ + b) * 1024 + dd];
            v = x * x;
        }
        sm[d] = v;
    }
    __syncthreads();

    for (int i = 0; i < 16; ++i) {
        int mm = mg * 64 + w * 16 + i;
        const float* wrow = &mlpW[(long)mm * 2048];
        float ax = 0.f, ay = 0.f, az = 0.f, aw = 0.f;
#pragma unroll
        for (int it = 0; it < 8; ++it) {
            int k = it * 256 + lane * 4;
            float4 wv = *(const float4*)&wrow[k];
            float4 sv = *(const float4*)&sm[k];
            ax += wv.x * sv.x; ay += wv.y * sv.y;
            az += wv.z * sv.z; aw += wv.w * sv.w;
        }
        float ssum = (ax + ay) + (az + aw);
        for (int off = 32; off; off >>= 1) ssum += __shfl_down(ssum, off);
        if (lane == 0) om[(long)b * M_ + mm] = ssum + mlpb[mm];
    }
}

// K4b: out[b] = sigmoid(om[b] . outW + outb)   (CLS = 1)
__global__ __launch_bounds__(256) void k_final(
    const float* __restrict__ om,
    const float* __restrict__ outW, const float* __restrict__ outb,
    float* __restrict__ out)
{
    const int b = blockIdx.x;
    const int tid = threadIdx.x;
    __shared__ float red[256];
    float p = om[(long)b * M_ + tid] * outW[tid]
            + om[(long)b * M_ + 256 + tid] * outW[256 + tid];
    red[tid] = p;
    __syncthreads();
    for (int off = 128; off > 0; off >>= 1) {
        if (tid < off) red[tid] += red[tid + off];
        __syncthreads();
    }
    if (tid == 0) out[b] = 1.0f / (1.0f + __expf(-(red[0] + outb[0])));
}

// ---------------------------------------------------------------------------
extern "C" void kernel_launch(void* const* d_in, const int* in_sizes, int n_in,
                              void* d_out, int out_size, void* d_ws, size_t ws_size,
                              hipStream_t stream)
{
    const int*   s1    = (const int*)d_in[0];
    const int*   s2    = (const int*)d_in[1];
    const int*   l1    = (const int*)d_in[2];
    const int*   l2    = (const int*)d_in[3];
    const float* s1_h0 = (const float*)d_in[4];
    const float* s1_c0 = (const float*)d_in[5];
    const float* s2_h0 = (const float*)d_in[6];
    const float* s2_c0 = (const float*)d_in[7];
    const float* emb   = (const float*)d_in[8];
    const float* Wih_f = (const float*)d_in[9];
    const float* Whh_f = (const float*)d_in[10];
    const float* b_f   = (const float*)d_in[11];
    const float* Wih_b = (const float*)d_in[12];
    const float* Whh_b = (const float*)d_in[13];
    const float* b_b   = (const float*)d_in[14];
    const float* S1W   = (const float*)d_in[15];
    const float* S2W   = (const float*)d_in[16];
    const float* mlpW  = (const float*)d_in[17];
    const float* mlpb  = (const float*)d_in[18];
    const float* outW  = (const float*)d_in[19];
    const float* outb  = (const float*)d_in[20];
    float* out = (float*)d_out;

    // Workspace carve (all 16B-aligned)
    ushort* p16 = (ushort*)d_ws;
    ushort* embB  = p16;  p16 += (long)32000 * EP;
    ushort* WihBf = p16;  p16 += (long)G4 * EP;
    ushort* WihBb = p16;  p16 += (long)G4 * EP;
    ushort* WhhBf = p16;  p16 += (long)G4 * H_;
    ushort* WhhBb = p16;  p16 += (long)G4 * H_;
    ushort* S1WB  = p16;  p16 += (long)C_ * 2 * H_;
    ushort* xf    = p16;  p16 += (long)R_ * T_ * G4;
    ushort* xb    = p16;  p16 += (long)R_ * T_ * G4;
    ushort* hfB   = p16;  p16 += (long)R_ * TS * H_;
    ushort* hbB   = p16;  p16 += (long)R_ * TS * H_;
    float* pf = (float*)p16;
    float* pooled = pf;   pf += (long)R_ * 2 * H_;
    float* om     = pf;   pf += (long)B_ * M_;

    // sentinel-fill h arrays (0xFF bytes -> every 8B chunk = SENT); the
    // cvt_all init-role then writes real h0 into slot 0. hfB/hbB contiguous.
    hipMemsetAsync(hfB, 0xFF, (size_t)2 * R_ * TS * H_ * sizeof(ushort), stream);

    // P0 v2: vectorized weight conversion + h0 init
    k_cvt_all<<<5184, 256, 0, stream>>>(emb, Wih_f, Wih_b, Whh_f, Whh_b, S1W,
                                        s1_h0, s2_h0,
                                        embB, WihBf, WihBb, WhhBf, WhhBb, S1WB,
                                        hfB, hbB);

    // K1: input GEMM (64x256 tile, BK=64)
    k_embed_mfma<<<dim3(8, 256, 2), 256, 0, stream>>>(
        s1, s2, l1, l2, embB, WihBf, WihBb, b_f, b_b, xf, xb);

    // K2 v15: recurrence with two-phase dense poll (v8 otherwise verbatim)
    k_recur<<<NB, 256, 0, stream>>>(xf, xb, hfB, hbB, WhhBf, WhhBb,
                                    s1_c0, s2_c0);

    // K3: fused attention (GEMM + scores + softmax + pool)
    k_attn_fused<<<R_, 256, 0, stream>>>(hfB, hbB, l1, l2, S1WB, S2W, pooled);

    // K4: MLP head
    k_mlp1<<<dim3(8, B_), 256, 0, stream>>>(pooled, mlpW, mlpb, om);
    k_final<<<B_, 256, 0, stream>>>(om, outW, outb, out);
}